// Round 5
// baseline (378.788 us; speedup 1.0000x reference)
//
#include <hip/hip_runtime.h>
#include <math.h>

#define N_NODES 50000
#define PAD_ROWS 50048                 // 391 * 128
#define E_RAW   400000
#define E_TOT   (E_RAW + N_NODES)      // 450000 incl. self loops
#define NEG_SLOPE 0.2f

typedef __bf16 bf16_t;
typedef bf16_t bf16x8 __attribute__((ext_vector_type(8)));
typedef bf16_t bf16x4 __attribute__((ext_vector_type(4)));
typedef float  f32x4  __attribute__((ext_vector_type(4)));

__device__ __forceinline__ void fma4(float4& a, float s, const float4& w) {
    a.x += s * w.x; a.y += s * w.y; a.z += s * w.z; a.w += s * w.w;
}
__device__ __forceinline__ float dot4(const float4& a, const float4& b) {
    return a.x*b.x + a.y*b.y + a.z*b.z + a.w*b.w;
}

// ---------------- CSR build ----------------

__global__ void k_hist(const int* __restrict__ ei, int* __restrict__ cnt) {
    int e = blockIdx.x * 256 + threadIdx.x;
    if (e >= E_TOT) return;
    int dst = (e < E_RAW) ? ei[E_RAW + e] : (e - E_RAW);
    atomicAdd(&cnt[dst], 1);
}

__global__ void k_scan1(const int* __restrict__ cnt, int* __restrict__ offs,
                        int* __restrict__ bsum) {
    __shared__ int s[256];
    int i = blockIdx.x * 256 + threadIdx.x;
    int v = (i < N_NODES) ? cnt[i] : 0;
    s[threadIdx.x] = v;
    __syncthreads();
    for (int d = 1; d < 256; d <<= 1) {
        int t = (threadIdx.x >= d) ? s[threadIdx.x - d] : 0;
        __syncthreads();
        s[threadIdx.x] += t;
        __syncthreads();
    }
    if (i < N_NODES) offs[i] = s[threadIdx.x] - v;   // exclusive
    if (threadIdx.x == 255) bsum[blockIdx.x] = s[255];
}

__global__ void k_scan2(int* __restrict__ bsum, int nb) {
    __shared__ int s[256];
    int v = (threadIdx.x < nb) ? bsum[threadIdx.x] : 0;
    s[threadIdx.x] = v;
    __syncthreads();
    for (int d = 1; d < 256; d <<= 1) {
        int t = (threadIdx.x >= d) ? s[threadIdx.x - d] : 0;
        __syncthreads();
        s[threadIdx.x] += t;
        __syncthreads();
    }
    if (threadIdx.x < nb) bsum[threadIdx.x] = s[threadIdx.x] - v;  // exclusive
}

__global__ void k_scan3(int* __restrict__ offs, const int* __restrict__ bsum) {
    int i = blockIdx.x * 256 + threadIdx.x;
    if (i < N_NODES) offs[i] += bsum[blockIdx.x];
}

__global__ void k_scatter(const int* __restrict__ ei, const int* __restrict__ offs,
                          int* __restrict__ cursor, int* __restrict__ srcs) {
    int e = blockIdx.x * 256 + threadIdx.x;
    if (e >= E_TOT) return;
    int src, dst;
    if (e < E_RAW) { src = ei[e]; dst = ei[E_RAW + e]; }
    else           { src = dst = e - E_RAW; }
    int pos = offs[dst] + atomicAdd(&cursor[dst], 1);
    srcs[pos] = src;
}

// ---------------- X fp32 -> hi/lo bf16 split (padded rows) ----------------

__global__ void k_split_x(const float* __restrict__ X,
                          bf16_t* __restrict__ Xh, bf16_t* __restrict__ Xl) {
    int row = blockIdx.x;                      // 0 .. PAD_ROWS-1
    int col = threadIdx.x;
    int r = min(row, N_NODES - 1);
    float v = X[r * 256 + col];
    bf16_t h = (bf16_t)v;
    Xh[row * 256 + col] = h;
    Xl[row * 256 + col] = (bf16_t)(v - (float)h);
}

// ---------------- W transpose + bf16 hi/lo split ----------------

__global__ void k_split_w(const float* __restrict__ W,
                          bf16_t* __restrict__ Wth, bf16_t* __restrict__ Wtl) {
    int idx = blockIdx.x * 256 + threadIdx.x;   // 65536 total
    int k = idx >> 8, n = idx & 255;
    float v = W[k * 256 + n];
    bf16_t h = (bf16_t)v;
    Wth[n * 256 + k] = h;
    Wtl[n * 256 + k] = (bf16_t)(v - (float)h);
}

// ---------------- MFMA GEMM, LDS-free: direct global->VGPR fragments ------
// Block = 128 rows x 128 cols, 4 waves in 2x2; wave = 64x64 (4x4 fragments).
// A[row][k] and Bt[col][k] row-major-in-k match the 16x16x32 fragment layout:
// lane l holds row/col (l&15), k-elems (l>>4)*8..+7  -> b128 direct loads.
// No LDS, no barriers: compiler pipelines loads across MFMAs with vmcnt.
// HAS_AL: A has a lo part (fp32-sourced) -> 3 MFMA/frag, else 2.

template<bool HAS_AL>
__global__ __launch_bounds__(256) void k_gemm256_mfma(
        const bf16_t* __restrict__ Ah, const bf16_t* __restrict__ Al,
        const bf16_t* __restrict__ Bth, const bf16_t* __restrict__ Btl,
        const float* __restrict__ a_s, const float* __restrict__ a_d,
        bf16_t* __restrict__ Hb, float* __restrict__ As, float* __restrict__ Ad) {
    const int lane = threadIdx.x & 63;
    const int wv   = threadIdx.x >> 6;                   // 0..3
    const int r16  = lane & 15;
    const int kg   = lane >> 4;                          // 0..3
    const int rowb = blockIdx.x * 128 + (wv >> 1) * 64;  // wave row base
    const int colb = blockIdx.y * 128 + (wv & 1) * 64;   // wave col base

    f32x4 acc[4][4] = {};

    const bf16_t* aPtr  = Ah  + (rowb + r16) * 256 + kg * 8;
    const bf16_t* alPtr = Al  + (rowb + r16) * 256 + kg * 8;
    const bf16_t* bhPtr = Bth + (colb + r16) * 256 + kg * 8;
    const bf16_t* blPtr = Btl + (colb + r16) * 256 + kg * 8;

    #pragma unroll 2
    for (int k0 = 0; k0 < 256; k0 += 32) {
        bf16x8 ah[4], al[4], bh[4], bl[4];
        #pragma unroll
        for (int m = 0; m < 4; ++m) {
            ah[m] = *(const bf16x8*)(aPtr + m * 16 * 256 + k0);
            if constexpr (HAS_AL) al[m] = *(const bf16x8*)(alPtr + m * 16 * 256 + k0);
        }
        #pragma unroll
        for (int n = 0; n < 4; ++n) {
            bh[n] = *(const bf16x8*)(bhPtr + n * 16 * 256 + k0);
            bl[n] = *(const bf16x8*)(blPtr + n * 16 * 256 + k0);
        }
        #pragma unroll
        for (int m = 0; m < 4; ++m) {
            #pragma unroll
            for (int n = 0; n < 4; ++n) {
                acc[m][n] = __builtin_amdgcn_mfma_f32_16x16x32_bf16(ah[m], bh[n], acc[m][n], 0, 0, 0);
                acc[m][n] = __builtin_amdgcn_mfma_f32_16x16x32_bf16(ah[m], bl[n], acc[m][n], 0, 0, 0);
                if constexpr (HAS_AL)
                    acc[m][n] = __builtin_amdgcn_mfma_f32_16x16x32_bf16(al[m], bh[n], acc[m][n], 0, 0, 0);
            }
        }
    }

    // ---- epilogue: store bf16 H, fused alpha dots ----
    float asv[4], adv[4];
    #pragma unroll
    for (int n = 0; n < 4; ++n) {
        int col = colb + n * 16 + r16;
        asv[n] = a_s[col];
        adv[n] = a_d[col];
    }
    #pragma unroll
    for (int m = 0; m < 4; ++m) {
        #pragma unroll
        for (int j = 0; j < 4; ++j) {
            int row = rowb + m * 16 + kg * 4 + j;
            bool ok = row < N_NODES;
            float ss = 0.f, sd = 0.f;
            #pragma unroll
            for (int n = 0; n < 4; ++n) {
                float v = acc[m][n][j];
                if (ok) Hb[row * 256 + colb + n * 16 + r16] = (bf16_t)v;
                ss += v * asv[n];
                sd += v * adv[n];
            }
            #pragma unroll
            for (int o = 1; o < 16; o <<= 1) {
                ss += __shfl_xor(ss, o);
                sd += __shfl_xor(sd, o);
            }
            if (ok && r16 == 0) {
                atomicAdd(&As[row], ss);
                atomicAdd(&Ad[row], sd);
            }
        }
    }
}

// ---------------- GEMM 32-out (layer 2), bf16 input, fused alpha dots ----------------

__global__ __launch_bounds__(256) void k_gemm32(
        const bf16_t* __restrict__ Xb, const float* __restrict__ W,  // W: [256][32]
        const float* __restrict__ a_s, const float* __restrict__ a_d,
        float* __restrict__ H, float* __restrict__ As, float* __restrict__ Ad) {
    __shared__ float ws[256][32];
    __shared__ float xs[32][36];
    const int tid = threadIdx.x;
    #pragma unroll
    for (int i = 0; i < 8; ++i) {
        int f = tid + i * 256;
        int r = f >> 3, cc = (f & 7) * 4;
        *(float4*)&ws[r][cc] = *(const float4*)&W[r * 32 + cc];
    }
    const int rl = tid >> 3;
    const int cg = (tid & 7) * 4;
    const int rowg = blockIdx.x * 32;
    const int row = rowg + rl;
    const bool valid = row < N_NODES;
    float4 acc = {};
    __syncthreads();

    for (int k0 = 0; k0 < 256; k0 += 32) {
        {
            int r = tid >> 3, kk = (tid & 7) * 4;
            int gr = rowg + r;
            float4 v = {0, 0, 0, 0};
            if (gr < N_NODES) {
                bf16x4 bv = *(const bf16x4*)&Xb[gr * 256 + k0 + kk];
                v.x = (float)bv[0]; v.y = (float)bv[1];
                v.z = (float)bv[2]; v.w = (float)bv[3];
            }
            *(float4*)&xs[r][kk] = v;
        }
        __syncthreads();
        #pragma unroll
        for (int kk = 0; kk < 32; kk += 4) {
            float4 xv = *(const float4*)&xs[rl][kk];
            fma4(acc, xv.x, *(const float4*)&ws[k0 + kk + 0][cg]);
            fma4(acc, xv.y, *(const float4*)&ws[k0 + kk + 1][cg]);
            fma4(acc, xv.z, *(const float4*)&ws[k0 + kk + 2][cg]);
            fma4(acc, xv.w, *(const float4*)&ws[k0 + kk + 3][cg]);
        }
        __syncthreads();
    }

    float ss = dot4(acc, *(const float4*)&a_s[cg]);
    float sd = dot4(acc, *(const float4*)&a_d[cg]);
    #pragma unroll
    for (int o = 4; o; o >>= 1) {
        ss += __shfl_xor(ss, o);
        sd += __shfl_xor(sd, o);
    }
    if (valid) {
        *(float4*)&H[row * 32 + cg] = acc;
        if ((tid & 7) == 0) { As[row] = ss; Ad[row] = sd; }
    }
}

// ---------------- Attention: per-edge exp weights + per-node 1/denom ----------------

__global__ __launch_bounds__(256) void k_attn(
        const float* __restrict__ As, const float* __restrict__ Ad,
        const int* __restrict__ offs, const int* __restrict__ cnts,
        const int* __restrict__ srcs,
        int2* __restrict__ meta, float* __restrict__ inv) {
    const int lane = threadIdx.x & 63;
    int node = blockIdx.x * 4 + (threadIdx.x >> 6);
    if (node >= N_NODES) return;
    node = __builtin_amdgcn_readfirstlane(node);
    const int start = offs[node];
    const int cnt   = cnts[node];
    const float ad  = Ad[node];

    float m = -1e30f;
    for (int base = 0; base < cnt; base += 64) {
        int i = base + lane;
        if (i < cnt) {
            float e = As[srcs[start + i]] + ad;
            e = e > 0.f ? e : NEG_SLOPE * e;
            m = fmaxf(m, e);
        }
    }
    #pragma unroll
    for (int o = 32; o; o >>= 1) m = fmaxf(m, __shfl_xor(m, o));

    float denom = 0.f;
    for (int base = 0; base < cnt; base += 64) {
        int i = base + lane;
        if (i < cnt) {
            int s = srcs[start + i];
            float e = As[s] + ad;
            e = e > 0.f ? e : NEG_SLOPE * e;
            float p = __expf(e - m);
            denom += p;
            meta[start + i] = make_int2(s, __float_as_int(p));
        }
    }
    #pragma unroll
    for (int o = 32; o; o >>= 1) denom += __shfl_xor(denom, o);
    if (lane == 0) inv[node] = 1.f / denom;
}

// ---------------- Gather (256-wide bf16), fused bias + swish ----------------

__global__ __launch_bounds__(256) void k_gather256(
        const bf16_t* __restrict__ Hb, const int2* __restrict__ meta,
        const int* __restrict__ offs, const int* __restrict__ cnts,
        const float* __restrict__ inv,
        const float* __restrict__ bias, bf16_t* __restrict__ Hout) {
    const int lane = threadIdx.x & 63;
    int node = blockIdx.x * 4 + (threadIdx.x >> 6);
    if (node >= N_NODES) return;
    node = __builtin_amdgcn_readfirstlane(node);
    const int start = offs[node];
    const int cnt   = cnts[node];
    const float iv  = inv[node];
    const int c0 = lane * 4;

    float4 acc = {0.f, 0.f, 0.f, 0.f};
    for (int j = 0; j < cnt; j += 4) {
        int2 mp[4];
        #pragma unroll
        for (int k = 0; k < 4; ++k) mp[k] = meta[start + j + k];  // pad-safe
        #pragma unroll
        for (int k = 0; k < 4; ++k) {
            float p = (j + k < cnt) ? __int_as_float(mp[k].y) : 0.f;
            bf16x4 hv = *(const bf16x4*)&Hb[mp[k].x * 256 + c0];
            acc.x += p * (float)hv[0];
            acc.y += p * (float)hv[1];
            acc.z += p * (float)hv[2];
            acc.w += p * (float)hv[3];
        }
    }

    const float4 bv = *(const float4*)&bias[c0];
    float4 o4;
    o4.x = acc.x * iv + bv.x;
    o4.y = acc.y * iv + bv.y;
    o4.z = acc.z * iv + bv.z;
    o4.w = acc.w * iv + bv.w;
    o4.x = o4.x / (1.f + __expf(-o4.x));
    o4.y = o4.y / (1.f + __expf(-o4.y));
    o4.z = o4.z / (1.f + __expf(-o4.z));
    o4.w = o4.w / (1.f + __expf(-o4.w));
    bf16x4 st = {(bf16_t)o4.x, (bf16_t)o4.y, (bf16_t)o4.z, (bf16_t)o4.w};
    *(bf16x4*)&Hout[node * 256 + c0] = st;
}

// ---------------- Final gather (32-wide fp32) + bias + log_softmax ----------------

__global__ __launch_bounds__(256) void k_gather_final(
        const float* __restrict__ Hc,   // [N][32]
        const int2* __restrict__ meta,
        const int* __restrict__ offs, const int* __restrict__ cnts,
        const float* __restrict__ inv,
        const float* __restrict__ bias, float* __restrict__ out) {
    const int lane = threadIdx.x & 63;
    int node = blockIdx.x * 4 + (threadIdx.x >> 6);
    if (node >= N_NODES) return;
    node = __builtin_amdgcn_readfirstlane(node);
    const int start = offs[node];
    const int cnt   = cnts[node];
    const float iv  = inv[node];
    const int c = lane & 31;

    float acc = 0.f;
    for (int j = 0; j < cnt; j += 4) {
        int2 mp[4];
        #pragma unroll
        for (int k = 0; k < 4; ++k) mp[k] = meta[start + j + k];
        #pragma unroll
        for (int k = 0; k < 4; ++k) {
            float p = (j + k < cnt) ? __int_as_float(mp[k].y) : 0.f;
            acc += p * Hc[mp[k].x * 32 + c];
        }
    }

    float v = acc * iv + bias[c];
    float mm = v;
    #pragma unroll
    for (int o = 16; o; o >>= 1) mm = fmaxf(mm, __shfl_xor(mm, o));
    float ex = __expf(v - mm), sum = ex;
    #pragma unroll
    for (int o = 16; o; o >>= 1) sum += __shfl_xor(sum, o);
    float r = v - mm - __logf(sum);
    if (lane < 32) out[node * 32 + c] = r;
}

// ---------------- launch ----------------

extern "C" void kernel_launch(void* const* d_in, const int* in_sizes, int n_in,
                              void* d_out, int out_size, void* d_ws, size_t ws_size,
                              hipStream_t stream) {
    const float* x   = (const float*)d_in[0];
    const int*   ei  = (const int*)  d_in[1];
    const float* W0  = (const float*)d_in[2];
    const float* as0 = (const float*)d_in[3];
    const float* ad0 = (const float*)d_in[4];
    const float* b0  = (const float*)d_in[5];
    const float* W1  = (const float*)d_in[6];
    const float* as1 = (const float*)d_in[7];
    const float* ad1 = (const float*)d_in[8];
    const float* b1  = (const float*)d_in[9];
    const float* W2  = (const float*)d_in[10];
    const float* as2 = (const float*)d_in[11];
    const float* ad2 = (const float*)d_in[12];
    const float* b2  = (const float*)d_in[13];
    float* out = (float*)d_out;

    char* ws = (char*)d_ws;
    // padded bf16 feature buffers: PAD_ROWS*256*2 = 25,624,576 B each
    bf16_t* hA_b  = (bf16_t*)(ws + 0);
    bf16_t* hB_b  = (bf16_t*)(ws + 25624576);   // aliases Xh during layer-0 GEMM
    bf16_t* Xh    = hB_b;                        // dead before gather0 writes hB_b
    bf16_t* Xl    = (bf16_t*)(ws + 51249152);
    float*  hC    = (float*) (ws + 76873728);   //  6,400,000
    float*  As    = (float*) (ws + 83273728);
    float*  Ad    = (float*) (ws + 83473728);
    float*  inv   = (float*) (ws + 83673728);
    int*    cnts  = (int*)   (ws + 83873728);
    int*    offs  = (int*)   (ws + 84073728);
    int*    cursor= (int*)   (ws + 84273728);
    int*    srcs  = (int*)   (ws + 84473728);   //  1,800,000
    int2*   meta  = (int2*)  (ws + 86273728);   //  3,600,032 (E_TOT+4)
    int*    bsum  = (int*)   (ws + 89873760);   //      1,024
    bf16_t* Wth   = (bf16_t*)(ws + 89874784);   //    131,072
    bf16_t* Wtl   = (bf16_t*)(ws + 90005856);   //    131,072 -> end 90,136,928

    const int NB = (N_NODES + 255) / 256;       // 196

    hipMemsetAsync(cnts,   0, N_NODES * sizeof(int), stream);
    hipMemsetAsync(cursor, 0, N_NODES * sizeof(int), stream);
    hipMemsetAsync((char*)meta + (size_t)E_TOT * 8, 0, 32, stream);  // pad

    k_hist   <<<(E_TOT + 255) / 256, 256, 0, stream>>>(ei, cnts);
    k_scan1  <<<NB, 256, 0, stream>>>(cnts, offs, bsum);
    k_scan2  <<<1, 256, 0, stream>>>(bsum, NB);
    k_scan3  <<<NB, 256, 0, stream>>>(offs, bsum);
    k_scatter<<<(E_TOT + 255) / 256, 256, 0, stream>>>(ei, offs, cursor, srcs);

    const int AGG_BLOCKS = (N_NODES + 3) / 4;        // 12500
    const dim3 GEMM_GRID(PAD_ROWS / 128, 2);         // 391 x 2

    // layer 0 (A = X hi/lo split)
    k_split_x<<<PAD_ROWS, 256, 0, stream>>>(x, Xh, Xl);
    k_split_w<<<256, 256, 0, stream>>>(W0, Wth, Wtl);
    hipMemsetAsync(As, 0, 400000, stream);   // As + Ad contiguous
    k_gemm256_mfma<true><<<GEMM_GRID, 256, 0, stream>>>(Xh, Xl, Wth, Wtl, as0, ad0, hA_b, As, Ad);
    k_attn<<<AGG_BLOCKS, 256, 0, stream>>>(As, Ad, offs, cnts, srcs, meta, inv);
    k_gather256<<<AGG_BLOCKS, 256, 0, stream>>>(hA_b, meta, offs, cnts, inv, b0, hB_b);
    // layer 1 (A exact bf16)
    k_split_w<<<256, 256, 0, stream>>>(W1, Wth, Wtl);
    hipMemsetAsync(As, 0, 400000, stream);
    k_gemm256_mfma<false><<<GEMM_GRID, 256, 0, stream>>>(hB_b, Xl, Wth, Wtl, as1, ad1, hA_b, As, Ad);
    k_attn<<<AGG_BLOCKS, 256, 0, stream>>>(As, Ad, offs, cnts, srcs, meta, inv);
    k_gather256<<<AGG_BLOCKS, 256, 0, stream>>>(hA_b, meta, offs, cnts, inv, b1, hB_b);
    // layer 2 (+ fused log_softmax)
    k_gemm32<<<(N_NODES + 31) / 32, 256, 0, stream>>>(hB_b, W2, as2, ad2, hC, As, Ad);
    k_attn<<<AGG_BLOCKS, 256, 0, stream>>>(As, Ad, offs, cnts, srcs, meta, inv);
    k_gather_final<<<AGG_BLOCKS, 256, 0, stream>>>(hC, meta, offs, cnts, inv, b2, out);
}

// Round 6
// 339.899 us; speedup vs baseline: 1.1144x; 1.1144x over previous
//
#include <hip/hip_runtime.h>
#include <math.h>

#define N_NODES 50000
#define PAD_ROWS 50048                 // 782 * 64
#define E_RAW   400000
#define E_TOT   (E_RAW + N_NODES)      // 450000 incl. self loops
#define NEG_SLOPE 0.2f

typedef __bf16 bf16_t;
typedef bf16_t bf16x8 __attribute__((ext_vector_type(8)));
typedef bf16_t bf16x4 __attribute__((ext_vector_type(4)));
typedef float  f32x4  __attribute__((ext_vector_type(4)));

__device__ __forceinline__ void gll16(const void* g, void* l) {
    __builtin_amdgcn_global_load_lds(
        (const __attribute__((address_space(1))) void*)g,
        (__attribute__((address_space(3))) void*)l, 16, 0, 0);
}

__device__ __forceinline__ void fma4(float4& a, float s, const float4& w) {
    a.x += s * w.x; a.y += s * w.y; a.z += s * w.z; a.w += s * w.w;
}
__device__ __forceinline__ float dot4(const float4& a, const float4& b) {
    return a.x*b.x + a.y*b.y + a.z*b.z + a.w*b.w;
}

// ---------------- CSR build ----------------

__global__ void k_hist(const int* __restrict__ ei, int* __restrict__ cnt) {
    int e = blockIdx.x * 256 + threadIdx.x;
    if (e >= E_TOT) return;
    int dst = (e < E_RAW) ? ei[E_RAW + e] : (e - E_RAW);
    atomicAdd(&cnt[dst], 1);
}

__global__ void k_scan1(const int* __restrict__ cnt, int* __restrict__ offs,
                        int* __restrict__ bsum) {
    __shared__ int s[256];
    int i = blockIdx.x * 256 + threadIdx.x;
    int v = (i < N_NODES) ? cnt[i] : 0;
    s[threadIdx.x] = v;
    __syncthreads();
    for (int d = 1; d < 256; d <<= 1) {
        int t = (threadIdx.x >= d) ? s[threadIdx.x - d] : 0;
        __syncthreads();
        s[threadIdx.x] += t;
        __syncthreads();
    }
    if (i < N_NODES) offs[i] = s[threadIdx.x] - v;   // exclusive
    if (threadIdx.x == 255) bsum[blockIdx.x] = s[255];
}

__global__ void k_scan2(int* __restrict__ bsum, int nb) {
    __shared__ int s[256];
    int v = (threadIdx.x < nb) ? bsum[threadIdx.x] : 0;
    s[threadIdx.x] = v;
    __syncthreads();
    for (int d = 1; d < 256; d <<= 1) {
        int t = (threadIdx.x >= d) ? s[threadIdx.x - d] : 0;
        __syncthreads();
        s[threadIdx.x] += t;
        __syncthreads();
    }
    if (threadIdx.x < nb) bsum[threadIdx.x] = s[threadIdx.x] - v;  // exclusive
}

__global__ void k_scan3(int* __restrict__ offs, const int* __restrict__ bsum) {
    int i = blockIdx.x * 256 + threadIdx.x;
    if (i < N_NODES) offs[i] += bsum[blockIdx.x];
}

__global__ void k_scatter(const int* __restrict__ ei, const int* __restrict__ offs,
                          int* __restrict__ cursor, int* __restrict__ srcs) {
    int e = blockIdx.x * 256 + threadIdx.x;
    if (e >= E_TOT) return;
    int src, dst;
    if (e < E_RAW) { src = ei[e]; dst = ei[E_RAW + e]; }
    else           { src = dst = e - E_RAW; }
    int pos = offs[dst] + atomicAdd(&cursor[dst], 1);
    srcs[pos] = src;
}

// ---------------- W transpose + bf16 hi/lo split ----------------

__global__ void k_split_w(const float* __restrict__ W,
                          bf16_t* __restrict__ Wth, bf16_t* __restrict__ Wtl) {
    int idx = blockIdx.x * 256 + threadIdx.x;   // 65536 total
    int k = idx >> 8, n = idx & 255;
    float v = W[k * 256 + n];
    bf16_t h = (bf16_t)v;
    Wth[n * 256 + k] = h;
    Wtl[n * 256 + k] = (bf16_t)(v - (float)h);
}

// ---------------- MFMA GEMM: fragment-major LDS, double-buffered 2-phase ----
// BM=64 rows/block, BN=256, BK=32. 4 waves; wave wv owns cols wv*64..+63 as a
// 4x4 grid of 16x16 fragments. LDS: each 16x32 operand subtile = 64 slots x
// 16B, slot=lane (row lane&15, k-group lane>>4): ds_read_b128 conflict-free.
// Pipeline: STAGE(next buf) issued BEFORE MFMA(cur buf); single
// vmcnt(0)+barrier per K-step AFTER the MFMA cluster -> loads fly under MFMA.
// A_FP32 (layer 0): A staged from fp32 via regs with in-flight hi/lo split
// (3 MFMA/frag); else A is exact bf16 via global_load_lds (2 MFMA/frag).

template<bool A_FP32>
__global__ __launch_bounds__(256) void k_gemm256_mfma(
        const float* __restrict__ Af, const bf16_t* __restrict__ Ab,
        const bf16_t* __restrict__ Bth, const bf16_t* __restrict__ Btl,
        const float* __restrict__ a_s, const float* __restrict__ a_d,
        bf16_t* __restrict__ Hb, float* __restrict__ As, float* __restrict__ Ad) {
    __shared__ __align__(16) bf16_t AhS[2][4 * 512];
    __shared__ __align__(16) bf16_t AlS[2][4 * 512];
    __shared__ __align__(16) bf16_t BhS[2][16 * 512];
    __shared__ __align__(16) bf16_t BlS[2][16 * 512];

    const int tid  = threadIdx.x;
    const int lane = tid & 63;
    const int wv   = tid >> 6;          // 0..3: col block wv*64
    const int r16  = lane & 15;
    const int kg   = lane >> 4;         // 0..3
    const int rowg = blockIdx.x * 64;

    const int arow   = rowg + wv * 16 + r16;          // wave stages A-subtile wv
    const int arow_c = min(arow, N_NODES - 1);        // clamp for fp32 source

    f32x4 acc[4][4] = {};

    auto stage = [&](int b, int k0) {
        #pragma unroll
        for (int j = 0; j < 4; ++j) {
            int s = wv * 4 + j;                        // col subtile 0..15
            int boff = (s * 16 + r16) * 256 + kg * 8 + k0;
            gll16(&Bth[boff], &BhS[b][s * 512]);
            gll16(&Btl[boff], &BlS[b][s * 512]);
        }
        if constexpr (A_FP32) {
            const float* src = &Af[arow_c * 256 + k0 + kg * 8];
            float4 v0 = *(const float4*)src;
            float4 v1 = *(const float4*)(src + 4);
            float f[8] = {v0.x, v0.y, v0.z, v0.w, v1.x, v1.y, v1.z, v1.w};
            bf16x8 hi, lo;
            #pragma unroll
            for (int i = 0; i < 8; ++i) {
                bf16_t h = (bf16_t)f[i];
                hi[i] = h;
                lo[i] = (bf16_t)(f[i] - (float)h);
            }
            *(bf16x8*)&AhS[b][wv * 512 + lane * 8] = hi;
            *(bf16x8*)&AlS[b][wv * 512 + lane * 8] = lo;
        } else {
            gll16(&Ab[arow * 256 + kg * 8 + k0], &AhS[b][wv * 512]);
        }
    };

    stage(0, 0);
    __syncthreads();

    #pragma unroll
    for (int kk = 0; kk < 8; ++kk) {
        const int cur = kk & 1;
        if (kk < 7) stage(cur ^ 1, (kk + 1) * 32);    // prefetch next K-step

        bf16x8 ah[4], al[4], bh[4], bl[4];
        #pragma unroll
        for (int m = 0; m < 4; ++m) {
            ah[m] = *(const bf16x8*)&AhS[cur][m * 512 + lane * 8];
            if constexpr (A_FP32) al[m] = *(const bf16x8*)&AlS[cur][m * 512 + lane * 8];
        }
        #pragma unroll
        for (int n = 0; n < 4; ++n) {
            int s = wv * 4 + n;
            bh[n] = *(const bf16x8*)&BhS[cur][s * 512 + lane * 8];
            bl[n] = *(const bf16x8*)&BlS[cur][s * 512 + lane * 8];
        }
        #pragma unroll
        for (int m = 0; m < 4; ++m) {
            #pragma unroll
            for (int n = 0; n < 4; ++n) {
                acc[m][n] = __builtin_amdgcn_mfma_f32_16x16x32_bf16(ah[m], bh[n], acc[m][n], 0, 0, 0);
                acc[m][n] = __builtin_amdgcn_mfma_f32_16x16x32_bf16(ah[m], bl[n], acc[m][n], 0, 0, 0);
                if constexpr (A_FP32)
                    acc[m][n] = __builtin_amdgcn_mfma_f32_16x16x32_bf16(al[m], bh[n], acc[m][n], 0, 0, 0);
            }
        }
        __syncthreads();   // drains prefetch (had full MFMA phase to land) + LDS
    }

    // ---- epilogue: store bf16 H, fused alpha dots ----
    float asv[4], adv[4];
    #pragma unroll
    for (int n = 0; n < 4; ++n) {
        int col = wv * 64 + n * 16 + r16;
        asv[n] = a_s[col];
        adv[n] = a_d[col];
    }
    #pragma unroll
    for (int m = 0; m < 4; ++m) {
        #pragma unroll
        for (int j = 0; j < 4; ++j) {
            int row = rowg + m * 16 + kg * 4 + j;
            bool ok = row < N_NODES;
            float ss = 0.f, sd = 0.f;
            #pragma unroll
            for (int n = 0; n < 4; ++n) {
                float v = acc[m][n][j];
                if (ok) Hb[row * 256 + wv * 64 + n * 16 + r16] = (bf16_t)v;
                ss += v * asv[n];
                sd += v * adv[n];
            }
            #pragma unroll
            for (int o = 1; o < 16; o <<= 1) {
                ss += __shfl_xor(ss, o);
                sd += __shfl_xor(sd, o);
            }
            if (ok && r16 == 0) {
                atomicAdd(&As[row], ss);
                atomicAdd(&Ad[row], sd);
            }
        }
    }
}

// ---------------- GEMM 32-out (layer 2), bf16 input, fused alpha dots ----------------

__global__ __launch_bounds__(256) void k_gemm32(
        const bf16_t* __restrict__ Xb, const float* __restrict__ W,  // W: [256][32]
        const float* __restrict__ a_s, const float* __restrict__ a_d,
        float* __restrict__ H, float* __restrict__ As, float* __restrict__ Ad) {
    __shared__ float ws[256][32];
    __shared__ float xs[32][36];
    const int tid = threadIdx.x;
    #pragma unroll
    for (int i = 0; i < 8; ++i) {
        int f = tid + i * 256;
        int r = f >> 3, cc = (f & 7) * 4;
        *(float4*)&ws[r][cc] = *(const float4*)&W[r * 32 + cc];
    }
    const int rl = tid >> 3;
    const int cg = (tid & 7) * 4;
    const int rowg = blockIdx.x * 32;
    const int row = rowg + rl;
    const bool valid = row < N_NODES;
    float4 acc = {};
    __syncthreads();

    for (int k0 = 0; k0 < 256; k0 += 32) {
        {
            int r = tid >> 3, kk = (tid & 7) * 4;
            int gr = rowg + r;
            float4 v = {0, 0, 0, 0};
            if (gr < N_NODES) {
                bf16x4 bv = *(const bf16x4*)&Xb[gr * 256 + k0 + kk];
                v.x = (float)bv[0]; v.y = (float)bv[1];
                v.z = (float)bv[2]; v.w = (float)bv[3];
            }
            *(float4*)&xs[r][kk] = v;
        }
        __syncthreads();
        #pragma unroll
        for (int kk = 0; kk < 32; kk += 4) {
            float4 xv = *(const float4*)&xs[rl][kk];
            fma4(acc, xv.x, *(const float4*)&ws[k0 + kk + 0][cg]);
            fma4(acc, xv.y, *(const float4*)&ws[k0 + kk + 1][cg]);
            fma4(acc, xv.z, *(const float4*)&ws[k0 + kk + 2][cg]);
            fma4(acc, xv.w, *(const float4*)&ws[k0 + kk + 3][cg]);
        }
        __syncthreads();
    }

    float ss = dot4(acc, *(const float4*)&a_s[cg]);
    float sd = dot4(acc, *(const float4*)&a_d[cg]);
    #pragma unroll
    for (int o = 4; o; o >>= 1) {
        ss += __shfl_xor(ss, o);
        sd += __shfl_xor(sd, o);
    }
    if (valid) {
        *(float4*)&H[row * 32 + cg] = acc;
        if ((tid & 7) == 0) { As[row] = ss; Ad[row] = sd; }
    }
}

// ---------------- Attention: per-edge exp weights + per-node 1/denom ----------------

__global__ __launch_bounds__(256) void k_attn(
        const float* __restrict__ As, const float* __restrict__ Ad,
        const int* __restrict__ offs, const int* __restrict__ cnts,
        const int* __restrict__ srcs,
        int2* __restrict__ meta, float* __restrict__ inv) {
    const int lane = threadIdx.x & 63;
    int node = blockIdx.x * 4 + (threadIdx.x >> 6);
    if (node >= N_NODES) return;
    node = __builtin_amdgcn_readfirstlane(node);
    const int start = offs[node];
    const int cnt   = cnts[node];
    const float ad  = Ad[node];

    float m = -1e30f;
    for (int base = 0; base < cnt; base += 64) {
        int i = base + lane;
        if (i < cnt) {
            float e = As[srcs[start + i]] + ad;
            e = e > 0.f ? e : NEG_SLOPE * e;
            m = fmaxf(m, e);
        }
    }
    #pragma unroll
    for (int o = 32; o; o >>= 1) m = fmaxf(m, __shfl_xor(m, o));

    float denom = 0.f;
    for (int base = 0; base < cnt; base += 64) {
        int i = base + lane;
        if (i < cnt) {
            int s = srcs[start + i];
            float e = As[s] + ad;
            e = e > 0.f ? e : NEG_SLOPE * e;
            float p = __expf(e - m);
            denom += p;
            meta[start + i] = make_int2(s, __float_as_int(p));
        }
    }
    #pragma unroll
    for (int o = 32; o; o >>= 1) denom += __shfl_xor(denom, o);
    if (lane == 0) inv[node] = 1.f / denom;
}

// ---------------- Gather (256-wide bf16), fused bias + swish ----------------

__global__ __launch_bounds__(256) void k_gather256(
        const bf16_t* __restrict__ Hb, const int2* __restrict__ meta,
        const int* __restrict__ offs, const int* __restrict__ cnts,
        const float* __restrict__ inv,
        const float* __restrict__ bias, bf16_t* __restrict__ Hout) {
    const int lane = threadIdx.x & 63;
    int node = blockIdx.x * 4 + (threadIdx.x >> 6);
    if (node >= N_NODES) return;
    node = __builtin_amdgcn_readfirstlane(node);
    const int start = offs[node];
    const int cnt   = cnts[node];
    const float iv  = inv[node];
    const int c0 = lane * 4;

    float4 acc = {0.f, 0.f, 0.f, 0.f};
    for (int j = 0; j < cnt; j += 4) {
        int2 mp[4];
        #pragma unroll
        for (int k = 0; k < 4; ++k) mp[k] = meta[start + j + k];  // pad-safe
        #pragma unroll
        for (int k = 0; k < 4; ++k) {
            float p = (j + k < cnt) ? __int_as_float(mp[k].y) : 0.f;
            bf16x4 hv = *(const bf16x4*)&Hb[mp[k].x * 256 + c0];
            acc.x += p * (float)hv[0];
            acc.y += p * (float)hv[1];
            acc.z += p * (float)hv[2];
            acc.w += p * (float)hv[3];
        }
    }

    const float4 bv = *(const float4*)&bias[c0];
    float4 o4;
    o4.x = acc.x * iv + bv.x;
    o4.y = acc.y * iv + bv.y;
    o4.z = acc.z * iv + bv.z;
    o4.w = acc.w * iv + bv.w;
    o4.x = o4.x / (1.f + __expf(-o4.x));
    o4.y = o4.y / (1.f + __expf(-o4.y));
    o4.z = o4.z / (1.f + __expf(-o4.z));
    o4.w = o4.w / (1.f + __expf(-o4.w));
    bf16x4 st = {(bf16_t)o4.x, (bf16_t)o4.y, (bf16_t)o4.z, (bf16_t)o4.w};
    *(bf16x4*)&Hout[node * 256 + c0] = st;
}

// ---------------- Final gather (32-wide fp32) + bias + log_softmax ----------------

__global__ __launch_bounds__(256) void k_gather_final(
        const float* __restrict__ Hc,   // [N][32]
        const int2* __restrict__ meta,
        const int* __restrict__ offs, const int* __restrict__ cnts,
        const float* __restrict__ inv,
        const float* __restrict__ bias, float* __restrict__ out) {
    const int lane = threadIdx.x & 63;
    int node = blockIdx.x * 4 + (threadIdx.x >> 6);
    if (node >= N_NODES) return;
    node = __builtin_amdgcn_readfirstlane(node);
    const int start = offs[node];
    const int cnt   = cnts[node];
    const float iv  = inv[node];
    const int c = lane & 31;

    float acc = 0.f;
    for (int j = 0; j < cnt; j += 4) {
        int2 mp[4];
        #pragma unroll
        for (int k = 0; k < 4; ++k) mp[k] = meta[start + j + k];
        #pragma unroll
        for (int k = 0; k < 4; ++k) {
            float p = (j + k < cnt) ? __int_as_float(mp[k].y) : 0.f;
            acc += p * Hc[mp[k].x * 32 + c];
        }
    }

    float v = acc * iv + bias[c];
    float mm = v;
    #pragma unroll
    for (int o = 16; o; o >>= 1) mm = fmaxf(mm, __shfl_xor(mm, o));
    float ex = __expf(v - mm), sum = ex;
    #pragma unroll
    for (int o = 16; o; o >>= 1) sum += __shfl_xor(sum, o);
    float r = v - mm - __logf(sum);
    if (lane < 32) out[node * 32 + c] = r;
}

// ---------------- launch ----------------

extern "C" void kernel_launch(void* const* d_in, const int* in_sizes, int n_in,
                              void* d_out, int out_size, void* d_ws, size_t ws_size,
                              hipStream_t stream) {
    const float* x   = (const float*)d_in[0];
    const int*   ei  = (const int*)  d_in[1];
    const float* W0  = (const float*)d_in[2];
    const float* as0 = (const float*)d_in[3];
    const float* ad0 = (const float*)d_in[4];
    const float* b0  = (const float*)d_in[5];
    const float* W1  = (const float*)d_in[6];
    const float* as1 = (const float*)d_in[7];
    const float* ad1 = (const float*)d_in[8];
    const float* b1  = (const float*)d_in[9];
    const float* W2  = (const float*)d_in[10];
    const float* as2 = (const float*)d_in[11];
    const float* ad2 = (const float*)d_in[12];
    const float* b2  = (const float*)d_in[13];
    float* out = (float*)d_out;

    char* ws = (char*)d_ws;
    // padded bf16 feature buffers: PAD_ROWS*256*2 = 25,624,576 B each
    bf16_t* hA_b  = (bf16_t*)(ws + 0);
    bf16_t* hB_b  = (bf16_t*)(ws + 25624576);
    float*  hC    = (float*) (ws + 51249152);   //  6,400,000
    float*  As    = (float*) (ws + 57649152);
    float*  Ad    = (float*) (ws + 57849152);
    float*  inv   = (float*) (ws + 58049152);
    int*    cnts  = (int*)   (ws + 58249152);
    int*    offs  = (int*)   (ws + 58449152);
    int*    cursor= (int*)   (ws + 58649152);
    int*    srcs  = (int*)   (ws + 58849152);   //  1,800,000
    int2*   meta  = (int2*)  (ws + 60649152);   //  3,600,032 (E_TOT+4)
    int*    bsum  = (int*)   (ws + 64249184);   //      1,024
    bf16_t* Wth   = (bf16_t*)(ws + 64250208);   //    131,072
    bf16_t* Wtl   = (bf16_t*)(ws + 64381280);   //    131,072 -> end 64,512,352

    const int NB = (N_NODES + 255) / 256;       // 196

    hipMemsetAsync(cnts,   0, N_NODES * sizeof(int), stream);
    hipMemsetAsync(cursor, 0, N_NODES * sizeof(int), stream);
    hipMemsetAsync((char*)meta + (size_t)E_TOT * 8, 0, 32, stream);  // pad

    k_hist   <<<(E_TOT + 255) / 256, 256, 0, stream>>>(ei, cnts);
    k_scan1  <<<NB, 256, 0, stream>>>(cnts, offs, bsum);
    k_scan2  <<<1, 256, 0, stream>>>(bsum, NB);
    k_scan3  <<<NB, 256, 0, stream>>>(offs, bsum);
    k_scatter<<<(E_TOT + 255) / 256, 256, 0, stream>>>(ei, offs, cursor, srcs);

    const int AGG_BLOCKS  = (N_NODES + 3) / 4;   // 12500
    const int GEMM_BLOCKS = PAD_ROWS / 64;       // 782

    // layer 0 (A = x fp32, in-kernel hi/lo split)
    k_split_w<<<256, 256, 0, stream>>>(W0, Wth, Wtl);
    hipMemsetAsync(As, 0, 400000, stream);   // As + Ad contiguous
    k_gemm256_mfma<true><<<GEMM_BLOCKS, 256, 0, stream>>>(x, nullptr, Wth, Wtl, as0, ad0, hA_b, As, Ad);
    k_attn<<<AGG_BLOCKS, 256, 0, stream>>>(As, Ad, offs, cnts, srcs, meta, inv);
    k_gather256<<<AGG_BLOCKS, 256, 0, stream>>>(hA_b, meta, offs, cnts, inv, b0, hB_b);
    // layer 1 (A exact bf16)
    k_split_w<<<256, 256, 0, stream>>>(W1, Wth, Wtl);
    hipMemsetAsync(As, 0, 400000, stream);
    k_gemm256_mfma<false><<<GEMM_BLOCKS, 256, 0, stream>>>(nullptr, hB_b, Wth, Wtl, as1, ad1, hA_b, As, Ad);
    k_attn<<<AGG_BLOCKS, 256, 0, stream>>>(As, Ad, offs, cnts, srcs, meta, inv);
    k_gather256<<<AGG_BLOCKS, 256, 0, stream>>>(hA_b, meta, offs, cnts, inv, b1, hB_b);
    // layer 2 (+ fused log_softmax)
    k_gemm32<<<(N_NODES + 31) / 32, 256, 0, stream>>>(hB_b, W2, as2, ad2, hC, As, Ad);
    k_attn<<<AGG_BLOCKS, 256, 0, stream>>>(As, Ad, offs, cnts, srcs, meta, inv);
    k_gather_final<<<AGG_BLOCKS, 256, 0, stream>>>(hC, meta, offs, cnts, inv, b2, out);
}

// Round 7
// 339.713 us; speedup vs baseline: 1.1150x; 1.0005x over previous
//
#include <hip/hip_runtime.h>
#include <math.h>

#define N_NODES 50000
#define PAD_ROWS 50048                 // 782 * 64
#define E_RAW   400000
#define E_TOT   (E_RAW + N_NODES)      // 450000 incl. self loops
#define NEG_SLOPE 0.2f

typedef __bf16 bf16_t;
typedef bf16_t bf16x8 __attribute__((ext_vector_type(8)));
typedef bf16_t bf16x4 __attribute__((ext_vector_type(4)));
typedef float  f32x4  __attribute__((ext_vector_type(4)));

__device__ __forceinline__ void fma4(float4& a, float s, const float4& w) {
    a.x += s * w.x; a.y += s * w.y; a.z += s * w.z; a.w += s * w.w;
}

// ---------------- CSR build ----------------

__global__ void k_hist(const int* __restrict__ ei, int* __restrict__ cnt) {
    int e = blockIdx.x * 256 + threadIdx.x;
    if (e >= E_TOT) return;
    int dst = (e < E_RAW) ? ei[E_RAW + e] : (e - E_RAW);
    atomicAdd(&cnt[dst], 1);
}

__global__ void k_scan1(const int* __restrict__ cnt, int* __restrict__ offs,
                        int* __restrict__ bsum) {
    __shared__ int s[256];
    int i = blockIdx.x * 256 + threadIdx.x;
    int v = (i < N_NODES) ? cnt[i] : 0;
    s[threadIdx.x] = v;
    __syncthreads();
    for (int d = 1; d < 256; d <<= 1) {
        int t = (threadIdx.x >= d) ? s[threadIdx.x - d] : 0;
        __syncthreads();
        s[threadIdx.x] += t;
        __syncthreads();
    }
    if (i < N_NODES) offs[i] = s[threadIdx.x] - v;   // exclusive
    if (threadIdx.x == 255) bsum[blockIdx.x] = s[255];
}

__global__ void k_scan2(int* __restrict__ bsum, int nb) {
    __shared__ int s[256];
    int v = (threadIdx.x < nb) ? bsum[threadIdx.x] : 0;
    s[threadIdx.x] = v;
    __syncthreads();
    for (int d = 1; d < 256; d <<= 1) {
        int t = (threadIdx.x >= d) ? s[threadIdx.x - d] : 0;
        __syncthreads();
        s[threadIdx.x] += t;
        __syncthreads();
    }
    if (threadIdx.x < nb) bsum[threadIdx.x] = s[threadIdx.x] - v;  // exclusive
}

__global__ void k_scan3(int* __restrict__ offs, const int* __restrict__ bsum) {
    int i = blockIdx.x * 256 + threadIdx.x;
    if (i < N_NODES) offs[i] += bsum[blockIdx.x];
}

__global__ void k_scatter(const int* __restrict__ ei, const int* __restrict__ offs,
                          int* __restrict__ cursor, int* __restrict__ srcs) {
    int e = blockIdx.x * 256 + threadIdx.x;
    if (e >= E_TOT) return;
    int src, dst;
    if (e < E_RAW) { src = ei[e]; dst = ei[E_RAW + e]; }
    else           { src = dst = e - E_RAW; }
    int pos = offs[dst] + atomicAdd(&cursor[dst], 1);
    srcs[pos] = src;
}

// ---------------- W splits: all three layers in one launch ----------------
// W0,W1: [256][256] -> [n][k] bf16 hi/lo.  W2: [256][32] -> [32][256] hi/lo.

__global__ void k_split_all(const float* __restrict__ W0, const float* __restrict__ W1,
                            const float* __restrict__ W2,
                            bf16_t* __restrict__ T0h, bf16_t* __restrict__ T0l,
                            bf16_t* __restrict__ T1h, bf16_t* __restrict__ T1l,
                            bf16_t* __restrict__ T2h, bf16_t* __restrict__ T2l) {
    int idx = blockIdx.x * 256 + threadIdx.x;    // 139264 total
    float v; bf16_t *ph, *pl; int o;
    if (idx < 65536) {
        int k = idx >> 8, n = idx & 255;
        v = W0[idx]; ph = T0h; pl = T0l; o = n * 256 + k;
    } else if (idx < 131072) {
        int i = idx - 65536;
        int k = i >> 8, n = i & 255;
        v = W1[i]; ph = T1h; pl = T1l; o = n * 256 + k;
    } else {
        int i = idx - 131072;                    // < 8192
        int k = i >> 5, n = i & 31;
        v = W2[i]; ph = T2h; pl = T2l; o = n * 256 + k;
    }
    bf16_t h = (bf16_t)v;
    ph[o] = h;
    pl[o] = (bf16_t)(v - (float)h);
}

// ---------------- MFMA GEMM: LDS-free, register ping-pong pipeline ----------
// Block 256 thr = 4 waves; BM=64 rows/block, BN=256; wave wv owns cols wv*64
// as 4x4 16x16 fragments. Global layout [row][k] / [col][k] matches the MFMA
// fragment layout (lane l: row/col l&15, k-elems (l>>4)*8..+7) -> direct b128
// loads, no LDS, no barriers in the K-loop. Explicit 2-set register prefetch:
// loads for step k+1 issue BEFORE the MFMA cluster of step k; fp32 A-convert
// runs AFTER the MFMAs so its vmcnt wait hides behind them.
// Alpha dots reduced across the 4 waves via tiny LDS; plain stores (no atomics).

template<bool A_FP32>
__global__ __launch_bounds__(256) void k_gemm256_mfma(
        const float* __restrict__ Af, const bf16_t* __restrict__ Ab,
        const bf16_t* __restrict__ Bth, const bf16_t* __restrict__ Btl,
        const float* __restrict__ a_s, const float* __restrict__ a_d,
        bf16_t* __restrict__ Hb, float* __restrict__ As, float* __restrict__ Ad) {
    const int tid  = threadIdx.x;
    const int lane = tid & 63;
    const int wv   = tid >> 6;
    const int r16  = lane & 15;
    const int kg   = lane >> 4;
    const int rowg = blockIdx.x * 64;
    const int colw = wv * 64;

    int aoff[4], boff[4];
    #pragma unroll
    for (int m = 0; m < 4; ++m) {
        int row = rowg + m * 16 + r16;
        if (A_FP32 && row >= N_NODES) row = N_NODES - 1;  // fp32 src unpadded
        aoff[m] = row * 256 + kg * 8;
    }
    #pragma unroll
    for (int n = 0; n < 4; ++n)
        boff[n] = (colw + n * 16 + r16) * 256 + kg * 8;

    f32x4  acc[4][4] = {};
    bf16x8 ah[2][4];        // bf16 path: double-buffered; fp32 path: [0] only
    bf16x8 al[4];           // fp32 only
    bf16x8 bh[2][4], bl[2][4];
    float4 ra[2][4][2];     // fp32 only: raw staging

    auto loadB = [&](int s, int k0) {
        #pragma unroll
        for (int n = 0; n < 4; ++n) {
            bh[s][n] = *(const bf16x8*)(Bth + boff[n] + k0);
            bl[s][n] = *(const bf16x8*)(Btl + boff[n] + k0);
        }
    };
    auto loadRA = [&](int s, int k0) {
        #pragma unroll
        for (int m = 0; m < 4; ++m) {
            ra[s][m][0] = *(const float4*)(Af + aoff[m] + k0);
            ra[s][m][1] = *(const float4*)(Af + aoff[m] + k0 + 4);
        }
    };
    auto convA = [&](int s) {
        #pragma unroll
        for (int m = 0; m < 4; ++m) {
            float f[8] = {ra[s][m][0].x, ra[s][m][0].y, ra[s][m][0].z, ra[s][m][0].w,
                          ra[s][m][1].x, ra[s][m][1].y, ra[s][m][1].z, ra[s][m][1].w};
            #pragma unroll
            for (int i = 0; i < 8; ++i) {
                bf16_t h = (bf16_t)f[i];
                ah[0][m][i] = h;
                al[m][i]    = (bf16_t)(f[i] - (float)h);
            }
        }
    };
    auto loadA16 = [&](int s, int k0) {
        #pragma unroll
        for (int m = 0; m < 4; ++m)
            ah[s][m] = *(const bf16x8*)(Ab + aoff[m] + k0);
    };
    auto mm = [&](int s) {
        #pragma unroll
        for (int m = 0; m < 4; ++m) {
            #pragma unroll
            for (int n = 0; n < 4; ++n) {
                const bf16x8& A = A_FP32 ? ah[0][m] : ah[s][m];
                acc[m][n] = __builtin_amdgcn_mfma_f32_16x16x32_bf16(A, bh[s][n], acc[m][n], 0, 0, 0);
                acc[m][n] = __builtin_amdgcn_mfma_f32_16x16x32_bf16(A, bl[s][n], acc[m][n], 0, 0, 0);
                if constexpr (A_FP32)
                    acc[m][n] = __builtin_amdgcn_mfma_f32_16x16x32_bf16(al[m], bh[s][n], acc[m][n], 0, 0, 0);
            }
        }
    };

    if constexpr (A_FP32) { loadRA(0, 0); loadB(0, 0); convA(0); }
    else                  { loadA16(0, 0); loadB(0, 0); }

    #pragma unroll
    for (int kk = 0; kk < 8; ++kk) {
        const int c  = kk & 1;
        const int nx = c ^ 1;
        const int k1 = (kk + 1) * 32;
        if (kk < 7) {
            if constexpr (A_FP32) loadRA(nx, k1);
            else                  loadA16(nx, k1);
            loadB(nx, k1);
        }
        mm(c);
        if constexpr (A_FP32) { if (kk < 7) convA(nx); }
    }

    // ---- epilogue: store bf16 H; alpha dots via shfl + cross-wave LDS reduce ----
    __shared__ float redS[4][64], redD[4][64];
    float asv[4], adv[4];
    #pragma unroll
    for (int n = 0; n < 4; ++n) {
        int col = colw + n * 16 + r16;
        asv[n] = a_s[col];
        adv[n] = a_d[col];
    }
    #pragma unroll
    for (int m = 0; m < 4; ++m) {
        #pragma unroll
        for (int j = 0; j < 4; ++j) {
            int rl  = m * 16 + kg * 4 + j;
            int row = rowg + rl;
            bool ok = row < N_NODES;
            float ss = 0.f, sd = 0.f;
            #pragma unroll
            for (int n = 0; n < 4; ++n) {
                float v = acc[m][n][j];
                if (ok) Hb[row * 256 + colw + n * 16 + r16] = (bf16_t)v;
                ss += v * asv[n];
                sd += v * adv[n];
            }
            #pragma unroll
            for (int o = 1; o < 16; o <<= 1) {
                ss += __shfl_xor(ss, o);
                sd += __shfl_xor(sd, o);
            }
            if (r16 == 0) { redS[wv][rl] = ss; redD[wv][rl] = sd; }
        }
    }
    __syncthreads();
    if (tid < 64) {
        int row = rowg + tid;
        if (row < N_NODES) {
            float s = redS[0][tid] + redS[1][tid] + redS[2][tid] + redS[3][tid];
            float d = redD[0][tid] + redD[1][tid] + redD[2][tid] + redD[3][tid];
            As[row] = s;
            Ad[row] = d;
        }
    }
}

// ---------------- GEMM 32-out (layer 2), MFMA, same reg-pipeline ------------
// Block 256 thr = 4 waves; each wave 64 rows x all 32 cols (2 n-frags).

__global__ __launch_bounds__(256) void k_gemm32_mfma(
        const bf16_t* __restrict__ Ab,                          // [PAD_ROWS][256]
        const bf16_t* __restrict__ Bth, const bf16_t* __restrict__ Btl,  // [32][256]
        const float* __restrict__ a_s, const float* __restrict__ a_d,
        float* __restrict__ Hc, float* __restrict__ As, float* __restrict__ Ad) {
    const int tid  = threadIdx.x;
    const int lane = tid & 63;
    const int wv   = tid >> 6;
    const int r16  = lane & 15;
    const int kg   = lane >> 4;
    const int rowg = blockIdx.x * 256 + wv * 64;

    int aoff[4], boff[2];
    #pragma unroll
    for (int m = 0; m < 4; ++m) {
        int row = rowg + m * 16 + r16;
        if (row >= N_NODES) row = N_NODES - 1;   // grid overshoots PAD_ROWS
        aoff[m] = row * 256 + kg * 8;
    }
    #pragma unroll
    for (int n = 0; n < 2; ++n)
        boff[n] = (n * 16 + r16) * 256 + kg * 8;

    f32x4  acc[4][2] = {};
    bf16x8 ah[2][4];
    bf16x8 bh[2][2], bl[2][2];

    auto loadA = [&](int s, int k0) {
        #pragma unroll
        for (int m = 0; m < 4; ++m)
            ah[s][m] = *(const bf16x8*)(Ab + aoff[m] + k0);
    };
    auto loadB = [&](int s, int k0) {
        #pragma unroll
        for (int n = 0; n < 2; ++n) {
            bh[s][n] = *(const bf16x8*)(Bth + boff[n] + k0);
            bl[s][n] = *(const bf16x8*)(Btl + boff[n] + k0);
        }
    };
    auto mm = [&](int s) {
        #pragma unroll
        for (int m = 0; m < 4; ++m) {
            #pragma unroll
            for (int n = 0; n < 2; ++n) {
                acc[m][n] = __builtin_amdgcn_mfma_f32_16x16x32_bf16(ah[s][m], bh[s][n], acc[m][n], 0, 0, 0);
                acc[m][n] = __builtin_amdgcn_mfma_f32_16x16x32_bf16(ah[s][m], bl[s][n], acc[m][n], 0, 0, 0);
            }
        }
    };

    loadA(0, 0); loadB(0, 0);
    #pragma unroll
    for (int kk = 0; kk < 8; ++kk) {
        const int c  = kk & 1;
        const int nx = c ^ 1;
        const int k1 = (kk + 1) * 32;
        if (kk < 7) { loadA(nx, k1); loadB(nx, k1); }
        mm(c);
    }

    float asv[2], adv[2];
    #pragma unroll
    for (int n = 0; n < 2; ++n) {
        int col = n * 16 + r16;
        asv[n] = a_s[col];
        adv[n] = a_d[col];
    }
    #pragma unroll
    for (int m = 0; m < 4; ++m) {
        #pragma unroll
        for (int j = 0; j < 4; ++j) {
            int row = rowg + m * 16 + kg * 4 + j;
            bool ok = row < N_NODES;
            float ss = 0.f, sd = 0.f;
            #pragma unroll
            for (int n = 0; n < 2; ++n) {
                float v = acc[m][n][j];
                if (ok) Hc[row * 32 + n * 16 + r16] = v;
                ss += v * asv[n];
                sd += v * adv[n];
            }
            #pragma unroll
            for (int o = 1; o < 16; o <<= 1) {
                ss += __shfl_xor(ss, o);
                sd += __shfl_xor(sd, o);
            }
            if (ok && r16 == 0) { As[row] = ss; Ad[row] = sd; }
        }
    }
}

// ---------------- Attention: per-edge exp weights + per-node 1/denom ----------------

__global__ __launch_bounds__(256) void k_attn(
        const float* __restrict__ As, const float* __restrict__ Ad,
        const int* __restrict__ offs, const int* __restrict__ cnts,
        const int* __restrict__ srcs,
        int2* __restrict__ meta, float* __restrict__ inv) {
    const int lane = threadIdx.x & 63;
    int node = blockIdx.x * 4 + (threadIdx.x >> 6);
    if (node >= N_NODES) return;
    node = __builtin_amdgcn_readfirstlane(node);
    const int start = offs[node];
    const int cnt   = cnts[node];
    const float ad  = Ad[node];

    float m = -1e30f;
    for (int base = 0; base < cnt; base += 64) {
        int i = base + lane;
        if (i < cnt) {
            float e = As[srcs[start + i]] + ad;
            e = e > 0.f ? e : NEG_SLOPE * e;
            m = fmaxf(m, e);
        }
    }
    #pragma unroll
    for (int o = 32; o; o >>= 1) m = fmaxf(m, __shfl_xor(m, o));

    float denom = 0.f;
    for (int base = 0; base < cnt; base += 64) {
        int i = base + lane;
        if (i < cnt) {
            int s = srcs[start + i];
            float e = As[s] + ad;
            e = e > 0.f ? e : NEG_SLOPE * e;
            float p = __expf(e - m);
            denom += p;
            meta[start + i] = make_int2(s, __float_as_int(p));
        }
    }
    #pragma unroll
    for (int o = 32; o; o >>= 1) denom += __shfl_xor(denom, o);
    if (lane == 0) inv[node] = 1.f / denom;
}

// ---------------- Gather (256-wide bf16), fused bias + swish ----------------

__global__ __launch_bounds__(256) void k_gather256(
        const bf16_t* __restrict__ Hb, const int2* __restrict__ meta,
        const int* __restrict__ offs, const int* __restrict__ cnts,
        const float* __restrict__ inv,
        const float* __restrict__ bias, bf16_t* __restrict__ Hout) {
    const int lane = threadIdx.x & 63;
    int node = blockIdx.x * 4 + (threadIdx.x >> 6);
    if (node >= N_NODES) return;
    node = __builtin_amdgcn_readfirstlane(node);
    const int start = offs[node];
    const int cnt   = cnts[node];
    const float iv  = inv[node];
    const int c0 = lane * 4;

    float4 acc = {0.f, 0.f, 0.f, 0.f};
    for (int j = 0; j < cnt; j += 4) {
        int2 mp[4];
        #pragma unroll
        for (int k = 0; k < 4; ++k) mp[k] = meta[start + j + k];  // pad-safe
        #pragma unroll
        for (int k = 0; k < 4; ++k) {
            float p = (j + k < cnt) ? __int_as_float(mp[k].y) : 0.f;
            bf16x4 hv = *(const bf16x4*)&Hb[mp[k].x * 256 + c0];
            acc.x += p * (float)hv[0];
            acc.y += p * (float)hv[1];
            acc.z += p * (float)hv[2];
            acc.w += p * (float)hv[3];
        }
    }

    const float4 bv = *(const float4*)&bias[c0];
    float4 o4;
    o4.x = acc.x * iv + bv.x;
    o4.y = acc.y * iv + bv.y;
    o4.z = acc.z * iv + bv.z;
    o4.w = acc.w * iv + bv.w;
    o4.x = o4.x / (1.f + __expf(-o4.x));
    o4.y = o4.y / (1.f + __expf(-o4.y));
    o4.z = o4.z / (1.f + __expf(-o4.z));
    o4.w = o4.w / (1.f + __expf(-o4.w));
    bf16x4 st = {(bf16_t)o4.x, (bf16_t)o4.y, (bf16_t)o4.z, (bf16_t)o4.w};
    *(bf16x4*)&Hout[node * 256 + c0] = st;
}

// ---------------- Final gather (32-wide fp32) + bias + log_softmax ----------------

__global__ __launch_bounds__(256) void k_gather_final(
        const float* __restrict__ Hc,   // [N][32]
        const int2* __restrict__ meta,
        const int* __restrict__ offs, const int* __restrict__ cnts,
        const float* __restrict__ inv,
        const float* __restrict__ bias, float* __restrict__ out) {
    const int lane = threadIdx.x & 63;
    int node = blockIdx.x * 4 + (threadIdx.x >> 6);
    if (node >= N_NODES) return;
    node = __builtin_amdgcn_readfirstlane(node);
    const int start = offs[node];
    const int cnt   = cnts[node];
    const float iv  = inv[node];
    const int c = lane & 31;

    float acc = 0.f;
    for (int j = 0; j < cnt; j += 4) {
        int2 mp[4];
        #pragma unroll
        for (int k = 0; k < 4; ++k) mp[k] = meta[start + j + k];
        #pragma unroll
        for (int k = 0; k < 4; ++k) {
            float p = (j + k < cnt) ? __int_as_float(mp[k].y) : 0.f;
            acc += p * Hc[mp[k].x * 32 + c];
        }
    }

    float v = acc * iv + bias[c];
    float mm = v;
    #pragma unroll
    for (int o = 16; o; o >>= 1) mm = fmaxf(mm, __shfl_xor(mm, o));
    float ex = __expf(v - mm), sum = ex;
    #pragma unroll
    for (int o = 16; o; o >>= 1) sum += __shfl_xor(sum, o);
    float r = v - mm - __logf(sum);
    if (lane < 32) out[node * 32 + c] = r;
}

// ---------------- launch ----------------

extern "C" void kernel_launch(void* const* d_in, const int* in_sizes, int n_in,
                              void* d_out, int out_size, void* d_ws, size_t ws_size,
                              hipStream_t stream) {
    const float* x   = (const float*)d_in[0];
    const int*   ei  = (const int*)  d_in[1];
    const float* W0  = (const float*)d_in[2];
    const float* as0 = (const float*)d_in[3];
    const float* ad0 = (const float*)d_in[4];
    const float* b0  = (const float*)d_in[5];
    const float* W1  = (const float*)d_in[6];
    const float* as1 = (const float*)d_in[7];
    const float* ad1 = (const float*)d_in[8];
    const float* b1  = (const float*)d_in[9];
    const float* W2  = (const float*)d_in[10];
    const float* as2 = (const float*)d_in[11];
    const float* ad2 = (const float*)d_in[12];
    const float* b2  = (const float*)d_in[13];
    float* out = (float*)d_out;

    char* ws = (char*)d_ws;
    // padded bf16 feature buffers: PAD_ROWS*256*2 = 25,624,576 B each
    bf16_t* hA_b  = (bf16_t*)(ws + 0);
    bf16_t* hB_b  = (bf16_t*)(ws + 25624576);
    float*  hC    = (float*) (ws + 51249152);   //  6,400,000
    float*  As    = (float*) (ws + 57649152);
    float*  Ad    = (float*) (ws + 57849152);
    float*  inv   = (float*) (ws + 58049152);
    int*    cnts  = (int*)   (ws + 58249152);
    int*    offs  = (int*)   (ws + 58449152);
    int*    cursor= (int*)   (ws + 58649152);
    int*    srcs  = (int*)   (ws + 58849152);   //  1,800,000
    int2*   meta  = (int2*)  (ws + 60649152);   //  3,600,032 (E_TOT+4)
    int*    bsum  = (int*)   (ws + 64249184);   //      1,024
    bf16_t* Wth0  = (bf16_t*)(ws + 64250208);   //    131,072
    bf16_t* Wtl0  = (bf16_t*)(ws + 64381280);   //    131,072
    bf16_t* Wth1  = (bf16_t*)(ws + 64512352);   //    131,072
    bf16_t* Wtl1  = (bf16_t*)(ws + 64643424);   //    131,072
    bf16_t* Wth2  = (bf16_t*)(ws + 64774496);   //     16,384
    bf16_t* Wtl2  = (bf16_t*)(ws + 64790880);   //     16,384 -> end 64,807,264

    const int NB = (N_NODES + 255) / 256;       // 196

    hipMemsetAsync(cnts,   0, N_NODES * sizeof(int), stream);
    hipMemsetAsync(cursor, 0, N_NODES * sizeof(int), stream);
    hipMemsetAsync((char*)meta + (size_t)E_TOT * 8, 0, 32, stream);  // pad

    k_hist     <<<(E_TOT + 255) / 256, 256, 0, stream>>>(ei, cnts);
    k_scan1    <<<NB, 256, 0, stream>>>(cnts, offs, bsum);
    k_scan2    <<<1, 256, 0, stream>>>(bsum, NB);
    k_scan3    <<<NB, 256, 0, stream>>>(offs, bsum);
    k_scatter  <<<(E_TOT + 255) / 256, 256, 0, stream>>>(ei, offs, cursor, srcs);
    k_split_all<<<544, 256, 0, stream>>>(W0, W1, W2, Wth0, Wtl0, Wth1, Wtl1, Wth2, Wtl2);

    const int AGG_BLOCKS  = (N_NODES + 3) / 4;   // 12500
    const int GEMM_BLOCKS = PAD_ROWS / 64;       // 782

    // layer 0 (A = x fp32, in-register hi/lo split)
    k_gemm256_mfma<true><<<GEMM_BLOCKS, 256, 0, stream>>>(x, nullptr, Wth0, Wtl0, as0, ad0, hA_b, As, Ad);
    k_attn<<<AGG_BLOCKS, 256, 0, stream>>>(As, Ad, offs, cnts, srcs, meta, inv);
    k_gather256<<<AGG_BLOCKS, 256, 0, stream>>>(hA_b, meta, offs, cnts, inv, b0, hB_b);
    // layer 1 (A exact bf16)
    k_gemm256_mfma<false><<<GEMM_BLOCKS, 256, 0, stream>>>(nullptr, hB_b, Wth1, Wtl1, as1, ad1, hA_b, As, Ad);
    k_attn<<<AGG_BLOCKS, 256, 0, stream>>>(As, Ad, offs, cnts, srcs, meta, inv);
    k_gather256<<<AGG_BLOCKS, 256, 0, stream>>>(hA_b, meta, offs, cnts, inv, b1, hB_b);
    // layer 2 (+ fused log_softmax)
    k_gemm32_mfma<<<NB, 256, 0, stream>>>(hB_b, Wth2, Wtl2, as2, ad2, hC, As, Ad);
    k_attn<<<AGG_BLOCKS, 256, 0, stream>>>(As, Ad, offs, cnts, srcs, meta, inv);
    k_gather_final<<<AGG_BLOCKS, 256, 0, stream>>>(hC, meta, offs, cnts, inv, b2, out);
}